// Round 1
// baseline (799.008 us; speedup 1.0000x reference)
//
#include <hip/hip_runtime.h>

#define NN 16384   // total nodes (4*64*64)
#define CC 48      // channels
// xg layout: per node, 52 floats = 48 features + [sq, 0, 0, 0]  (13 float4, 16B aligned)

// ---------- kernel 1: [B,C,H,W] -> xg[N][52] (features + squared-norm) ----------
__global__ __launch_bounds__(256) void prep_kernel(const float* __restrict__ x,
                                                   float* __restrict__ xg) {
  __shared__ float tile[48][65];   // +1 pad
  __shared__ float sqcol[64];
  int tid = threadIdx.x;
  int b   = blockIdx.x >> 6;          // batch image 0..3
  int hw0 = (blockIdx.x & 63) << 6;   // 64-wide hw tile
  // coalesced read: 48 rows x 64 cols
#pragma unroll
  for (int p = 0; p < 12; ++p) {
    int it = tid + p * 256;
    int r = it >> 6, col = it & 63;
    tile[r][col] = x[(b * 48 + r) * 4096 + hw0 + col];
  }
  __syncthreads();
  if (tid < 64) {
    float s = 0.f;
#pragma unroll
    for (int r = 0; r < 48; ++r) { float v = tile[r][tid]; s += v * v; }
    sqcol[tid] = s;
  }
  __syncthreads();
  // coalesced write: 64 node-rows x 13 float4
  float4* xg4 = (float4*)xg;
#pragma unroll
  for (int p = 0; p < 4; ++p) {
    int it = tid + p * 256;
    if (it < 832) {
      int col = it / 13;
      int q   = it - col * 13;
      float4 v;
      if (q < 12) {
        v.x = tile[q * 4 + 0][col]; v.y = tile[q * 4 + 1][col];
        v.z = tile[q * 4 + 2][col]; v.w = tile[q * 4 + 3][col];
      } else {
        v.x = sqcol[col]; v.y = 0.f; v.z = 0.f; v.w = 0.f;
      }
      xg4[(b * 4096 + hw0 + col) * 13 + q] = v;
    }
  }
}

// ---------- kernel 2: fused distance + top-9 ----------
// block = 512 thr = 8 waves; block owns 64 query nodes i.
// wave w: lanes = 16 i (i-group w&3) x 4 j-offsets; half = w>>2 splits the j range.
// each thread keeps a sorted top-9 (dist,idx) over its j-subset in registers;
// block-level 8-way merge per i at the end.
__global__ __launch_bounds__(512, 1) void knn_kernel(const float* __restrict__ xg,
                                                     int* __restrict__ nbr,
                                                     int* __restrict__ deg) {
  __shared__ float Ld[512 * 9];
  __shared__ int   Li[512 * 9];
  int tid  = threadIdx.x;
  int w    = tid >> 6;
  int lane = tid & 63;
  int iw   = lane >> 2;
  int jl   = lane & 3;
  int half = w >> 2;
  int i = blockIdx.x * 64 + (w & 3) * 16 + iw;

  // batch id per torch.linspace(0,B,N).long(): floor(4*i/16383)
  int batch = (4 * i) / 16383;
  int js = batch * 4096;
  int je = js + 4096;
  if (batch == 3) je = 16383;
  if (batch == 4) { js = 16383; je = 16384; }
  int jmid = js + ((je - js) >> 1);
  int jb   = half ? jmid : js;
  int jeh  = half ? je : jmid;

  const float4* xg4 = (const float4*)xg;
  float4 xi[12];
#pragma unroll
  for (int q = 0; q < 12; ++q) xi[q] = xg4[i * 13 + q];

  float d9[9]; int n9[9];
#pragma unroll
  for (int k = 0; k < 9; ++k) { d9[k] = __builtin_inff(); n9[k] = 0x7fffffff; }

  for (int j = jb + jl; j < jeh; j += 4) {
    const float4* row = xg4 + j * 13;
    float4 rw[12];
#pragma unroll
    for (int q = 0; q < 12; ++q) rw[q] = row[q];
    float sqj = xg[j * 52 + 48];
    float ax = 0.f, ay = 0.f, az = 0.f, aw = 0.f;
#pragma unroll
    for (int q = 0; q < 12; ++q) {
      ax += rw[q].x * xi[q].x;
      ay += rw[q].y * xi[q].y;
      az += rw[q].z * xi[q].z;
      aw += rw[q].w * xi[q].w;
    }
    float dot = (ax + ay) + (az + aw);
    // ranking key: sq[j] - 2*dot  (sq[i] is constant per row -> dropped)
    float dist = sqj - 2.f * dot;
    // insert with jax.lax.top_k tie-break (lower index wins on equal dist)
    bool ins = (dist < d9[8]) || (dist == d9[8] && j < n9[8]);
    if (ins) {
      float cd = dist; int ci = j;
#pragma unroll
      for (int k = 0; k < 9; ++k) {
        bool less = (cd < d9[k]) || (cd == d9[k] && ci < n9[k]);
        float td = d9[k]; int ti = n9[k];
        float nd = less ? cd : td; int ni = less ? ci : ti;
        cd = less ? td : cd;       ci = less ? ti : ci;
        d9[k] = nd;                n9[k] = ni;
      }
    }
  }

#pragma unroll
  for (int k = 0; k < 9; ++k) { Ld[tid * 9 + k] = d9[k]; Li[tid * 9 + k] = n9[k]; }
  __syncthreads();

  if (tid < 64) {
    int im  = blockIdx.x * 64 + tid;
    int g   = tid >> 4;   // i-group
    int iw2 = tid & 15;
    int base[8];
#pragma unroll
    for (int h = 0; h < 2; ++h)
#pragma unroll
      for (int l = 0; l < 4; ++l)
        base[h * 4 + l] = (((g + h * 4) * 64) + iw2 * 4 + l) * 9;
    int ptr[8] = {0, 0, 0, 0, 0, 0, 0, 0};
    int outi[9];
    for (int k = 0; k < 9; ++k) {
      float bd = __builtin_inff(); int bi = 0x7fffffff; int bl = 0;
#pragma unroll
      for (int l = 0; l < 8; ++l) {
        float dv = Ld[base[l] + ptr[l]];
        int   iv = Li[base[l] + ptr[l]];
        bool better = (dv < bd) || (dv == bd && iv < bi);
        bd = better ? dv : bd; bi = better ? iv : bi; bl = better ? l : bl;
      }
      ptr[bl]++;
      outi[k] = bi;
    }
    // node 16383 sits alone in "batch 4": top_k over one valid entry + (-inf) ties
    // -> neighbors {16383, 0,1,...,7} (lowest-index tie-break). Matters for deg[0..7].
    if (im == NN - 1) {
      outi[0] = NN - 1;
#pragma unroll
      for (int k = 1; k < 9; ++k) outi[k] = k - 1;
    }
#pragma unroll
    for (int k = 0; k < 9; ++k) {
      nbr[im * 9 + k] = outi[k];
      atomicAdd(&deg[outi[k]], 1);
    }
  }
}

// ---------- kernel 3: dinv ----------
__global__ __launch_bounds__(256) void dinv_kernel(const int* __restrict__ deg,
                                                   float* __restrict__ dinv) {
  int i = blockIdx.x * 256 + threadIdx.x;
  int d = deg[i];
  dinv[i] = d > 0 ? 1.0f / sqrtf((float)d) : 0.0f;
}

// ---------- kernel 4: tx1 gather + out = relu(xf@W0 + tx1@W1 + b) ----------
__global__ __launch_bounds__(256) void out_kernel(const float* __restrict__ xg,
                                                  const int* __restrict__ nbr,
                                                  const float* __restrict__ dinv,
                                                  const float* __restrict__ W0,
                                                  const float* __restrict__ W1,
                                                  const float* __restrict__ bias,
                                                  float* __restrict__ out) {
  __shared__ float w0s[48 * 48], w1s[48 * 48], bsh[48];
  __shared__ __align__(16) float xr[64 * 48];
  __shared__ float tx[64 * 48];
  __shared__ float wd[64][9];
  __shared__ int   jn[64][9];
  __shared__ float din[64];
  int tid = threadIdx.x;
  int r0  = blockIdx.x * 64;

  for (int p = tid; p < 2304; p += 256) { w0s[p] = W0[p]; w1s[p] = W1[p]; }
  if (tid < 48) bsh[tid] = bias[tid];
  if (tid < 64) din[tid] = dinv[r0 + tid];
  const float4* xg4 = (const float4*)xg;
  float4* xr4 = (float4*)xr;
  for (int p = tid; p < 768; p += 256) {
    int r = p / 12, q = p - r * 12;
    xr4[r * 12 + q] = xg4[(r0 + r) * 13 + q];
  }
  for (int p = tid; p < 576; p += 256) {
    int r = p / 9, k = p - r * 9;
    int j = nbr[(r0 + r) * 9 + k];
    jn[r][k] = j;
    wd[r][k] = dinv[j];
  }
  __syncthreads();

  // tx1 rows: tx1[i] = -dinv[i] * sum_k dinv[j_k] * xf[j_k]
  for (int p = tid; p < 3072; p += 256) {
    int r = p / 48, c = p - r * 48;
    float s = 0.f;
#pragma unroll
    for (int k = 0; k < 9; ++k) s += wd[r][k] * xg[jn[r][k] * 52 + c];
    tx[r * 48 + c] = -din[r] * s;
  }
  __syncthreads();

  // out[r][o] = relu(b[o] + sum_c xr[r][c]*W0[c][o] + tx[r][c]*W1[c][o])
  for (int p = tid; p < 3072; p += 256) {
    int r = p / 48, o = p - r * 48;
    float acc = bsh[o];
#pragma unroll
    for (int c = 0; c < 48; ++c)
      acc += xr[r * 48 + c] * w0s[c * 48 + o] + tx[r * 48 + c] * w1s[c * 48 + o];
    out[(r0 + r) * 48 + o] = fmaxf(acc, 0.f);
  }
}

extern "C" void kernel_launch(void* const* d_in, const int* in_sizes, int n_in,
                              void* d_out, int out_size, void* d_ws, size_t ws_size,
                              hipStream_t stream) {
  const float* x  = (const float*)d_in[0];
  const float* W0 = (const float*)d_in[1];
  const float* W1 = (const float*)d_in[2];
  const float* b  = (const float*)d_in[3];
  float* out = (float*)d_out;
  char* ws = (char*)d_ws;
  // workspace layout (16B aligned): ~4.13 MB total
  float* xg   = (float*)(ws);                 // 16384*52*4 = 3,407,872 B
  int*   nbr  = (int*)(ws + 3407872);         // 16384*9*4  =   589,824 B
  int*   deg  = (int*)(ws + 3997696);         //               65,536 B
  float* dinv = (float*)(ws + 4063232);       //               65,536 B

  hipMemsetAsync(deg, 0, NN * sizeof(int), stream);
  prep_kernel<<<256, 256, 0, stream>>>(x, xg);
  knn_kernel<<<256, 512, 0, stream>>>(xg, nbr, deg);
  dinv_kernel<<<64, 256, 0, stream>>>(deg, dinv);
  out_kernel<<<256, 256, 0, stream>>>(xg, nbr, dinv, W0, W1, b, out);
}